// Round 20
// baseline (170.345 us; speedup 1.0000x reference)
//
#include <hip/hip_runtime.h>
#include <math.h>

typedef unsigned short u16;
typedef unsigned int   u32;
typedef unsigned char  u8;
typedef __attribute__((ext_vector_type(8))) short short8v;
typedef __attribute__((ext_vector_type(4))) float f32x4;
typedef __attribute__((ext_vector_type(2))) float f32x2;

__device__ __forceinline__ u16 f2bf(float x) {
    u32 u = __float_as_uint(x);
    u += 0x7FFFu + ((u >> 16) & 1u);   // RNE
    return (u16)(u >> 16);
}

#if __has_builtin(__builtin_amdgcn_cvt_pk_fp8_f32) && __has_builtin(__builtin_amdgcn_cvt_pk_f32_fp8)
#define HW_FP8 1
#endif

// encode one fp8 e4m3fn from v >= 0 (relu output)
__device__ __forceinline__ u8 f2fp8(float v) {
#ifdef HW_FP8
    return (u8)(__builtin_amdgcn_cvt_pk_fp8_f32(v, v, 0, false) & 0xFF);
#else
    if (v < 0.015625f) return (u8)__float2int_rn(v * 512.0f);   // subnormal
    u32 b = __float_as_uint(fminf(v, 448.0f));
    b += 0x7FFFF + ((b >> 20) & 1);                              // RNE to 3 mant bits
    return (u8)((((b >> 23) - 120) << 3) | ((b >> 20) & 7));
#endif
}

__device__ __forceinline__ void fp8x4_acc(u32 w, float* acc) {
#ifdef HW_FP8
    const f32x2 lo = __builtin_amdgcn_cvt_pk_f32_fp8(w, false);
    const f32x2 hi = __builtin_amdgcn_cvt_pk_f32_fp8(w, true);
    acc[0] += lo[0]; acc[1] += lo[1]; acc[2] += hi[0]; acc[3] += hi[1];
#else
#pragma unroll
    for (int i = 0; i < 4; ++i) {
        const u32 b = (w >> (8 * i)) & 0xFF;
        const u32 e = (b >> 3) & 15, m = b & 7;
        acc[i] += e ? __uint_as_float(((e + 120) << 23) | (m << 20))
                    : (float)m * 0x1p-9f;
    }
#endif
}

#define NPB        256
#define NPB_SHIFT  8
#define EBUF_CAP   4608
#define MAX_BUK    512
#define BCS        16      // bcursor stride in ints (64 B -> one cacheline per bucket)
#define BIN_CHUNK  4096    // edges per bin block (4 per thread at 1024 threads)

// ---------------- A: convert weights + zero bcursor ----------------
__global__ __launch_bounds__(256) void conv_kernel(
    const float* __restrict__ W_in, const float* __restrict__ W_msg,
    const float* __restrict__ W_upd,
    const float* __restrict__ Wa1, const float* __restrict__ Wc1,
    u16* __restrict__ Wt_in, u16* __restrict__ Wt_msg,
    u16* __restrict__ Wt_upd, u16* __restrict__ Wh,
    int* __restrict__ bcursor)
{
    const int idx = blockIdx.x * 256 + threadIdx.x;
    if (idx < 16384) {                       // Wt_in [128 cols][128 k]
        const int c = idx >> 7, k = idx & 127;
        Wt_in[c * 128 + k] = f2bf(W_in[k * 128 + c]);
    } else if (idx < 32768) {                // Wt_msg
        const int i = idx - 16384;
        const int c = i >> 7, k = i & 127;
        Wt_msg[c * 128 + k] = f2bf(W_msg[k * 128 + c]);
    } else if (idx < 65536) {                // Wt_upd [128 cols][256 k]
        const int i = idx - 32768;
        const int c = i >> 8, k = i & 255;
        Wt_upd[c * 256 + k] = f2bf(W_upd[k * 128 + c]);
    } else if (idx < 69632) {                // Wh [32 cols][128 k]
        const int i = idx - 65536;
        const int col = i >> 7, k = i & 127;
        const float v = (col < 16) ? Wa1[k * 16 + col] : Wc1[k * 16 + (col - 16)];
        Wh[col * 128 + k] = f2bf(v);
    } else if (idx < 69632 + MAX_BUK * BCS) { // zero bucket cursors
        bcursor[idx - 69632] = 0;
    }
}

// ---------------- B: gemm1 || bin edges, INTERLEAVED (1024 thr) ----------------
__global__ __launch_bounds__(1024) void bin_gemm1_kernel(
    const int* __restrict__ src, const int* __restrict__ dst,
    int* __restrict__ bcursor, int* __restrict__ ebuf,
    int E, int nbuk, int binGrid, int g1Grid,
    const float* __restrict__ X, const u16* __restrict__ Wt_in,
    const float* __restrict__ b_in, u16* __restrict__ ns, int rows)
{
    __shared__ u16 smem[128 * 136];   // 34816 B
    const int tid = threadIdx.x;

    const int mn   = min(binGrid, g1Grid);
    const int half = 2 * mn;
    int role, widx;   // role 0 = gemm1, 1 = bin
    if ((int)blockIdx.x < half) {
        role = (int)blockIdx.x & 1;
        widx = (int)blockIdx.x >> 1;
    } else {
        const int r = (int)blockIdx.x - half;
        role = (binGrid > g1Grid) ? 1 : 0;
        widx = mn + r;
    }

    if (role == 1) {
        int* lcount = (int*)smem;            // [MAX_BUK]
        int* lbase  = lcount + MAX_BUK;      // [MAX_BUK]
        const int e0 = widx * BIN_CHUNK;
        const int e1 = min(e0 + BIN_CHUNK, E);
        for (int b = tid; b < nbuk; b += 1024) lcount[b] = 0;
        __syncthreads();

        int pay[4];
        u32 brk[4];
#pragma unroll
        for (int k = 0; k < 4; ++k) {
            const int i = e0 + tid + k * 1024;
            int payv = 0; u32 brkv = 0xFFFFFFFFu;
            if (i < e1) {
                const int d = dst[i];
                const int b = d >> NPB_SHIFT;
                const int r = atomicAdd(&lcount[b], 1);
                payv = (src[i] << NPB_SHIFT) | (d & (NPB - 1));
                brkv = ((u32)b << 16) | (u32)r;
            }
            pay[k] = payv; brk[k] = brkv;
        }
        __syncthreads();

        for (int b = tid; b < nbuk; b += 1024) {
            const int c = lcount[b];
            lbase[b] = c ? atomicAdd(&bcursor[b * BCS], c) : 0;
        }
        __syncthreads();

#pragma unroll
        for (int k = 0; k < 4; ++k) {
            if (brk[k] != 0xFFFFFFFFu) {
                const int b = (int)(brk[k] >> 16);
                const int p = lbase[b] + (int)(brk[k] & 0xFFFFu);
                ebuf[b * EBUF_CAP + min(p, EBUF_CAP - 1)] = pay[k];
            }
        }
        return;
    }

    // ---- gemm1: 16 waves x 16 rows = 256 rows/block ----
    u16 (*WtL)[136] = (u16(*)[136])smem;
    for (int i = tid; i < 2048; i += 1024)
        *(uint4*)&WtL[i >> 4][(i & 15) * 8] = ((const uint4*)Wt_in)[i];

    const int lane = tid & 63, wave = tid >> 6;
    const int lrow = lane & 15, lk = lane >> 4;
    const int r0 = widx * 256 + wave * 16;
    const int arow = r0 + lrow;
    const bool rowok = arow < rows;

    short8v a[4];
#pragma unroll
    for (int ks = 0; ks < 4; ++ks) {
        const int k = ks * 32 + lk * 8;
        short8v av = {};
        if (rowok) {
            const float* pf = X + (size_t)arow * 128 + k;
            const float4 x0 = *(const float4*)pf;
            const float4 x1 = *(const float4*)(pf + 4);
            u16 t[8] = {f2bf(x0.x), f2bf(x0.y), f2bf(x0.z), f2bf(x0.w),
                        f2bf(x1.x), f2bf(x1.y), f2bf(x1.z), f2bf(x1.w)};
            av = *(short8v*)t;
        }
        a[ks] = av;
    }
    __syncthreads();

    f32x4 acc[8];
#pragma unroll
    for (int n = 0; n < 8; ++n) acc[n] = (f32x4){0.f, 0.f, 0.f, 0.f};
#pragma unroll
    for (int ks = 0; ks < 4; ++ks) {
#pragma unroll
        for (int n = 0; n < 8; ++n) {
            const short8v b = *(const short8v*)&WtL[n * 16 + lrow][ks * 32 + lk * 8];
            acc[n] = __builtin_amdgcn_mfma_f32_16x16x32_bf16(a[ks], b, acc[n], 0, 0, 0);
        }
    }
#pragma unroll
    for (int reg = 0; reg < 4; ++reg) {
        const int row = r0 + lk * 4 + reg;
        if (row >= rows) continue;
#pragma unroll
        for (int n = 0; n < 8; ++n) {
            const float v = fmaxf(acc[n][reg] + b_in[n * 16 + lrow], 0.f);
            ns[(size_t)row * 128 + n * 16 + lrow] = f2bf(v);
        }
    }
}

// ---------------- C: gemm2 first, build_csr last (256 thr) ----------------
__global__ __launch_bounds__(256) void csr_gemm2_kernel(
    const int* __restrict__ ebuf, const int* __restrict__ bcursor,
    int* __restrict__ offs, int* __restrict__ csr, int N, int E, int nbuk,
    const u16* __restrict__ ns, const u16* __restrict__ Wt_msg,
    const float* __restrict__ b_msg, u8* __restrict__ msg8, int rows, int g2Grid)
{
    __shared__ u16 smem[128 * 136];   // 34816 B
    const int tid = threadIdx.x;

    if ((int)blockIdx.x >= g2Grid) {
        int* ibuf = (int*)smem;
        int* red  = ibuf;        // [4]
        int* ndeg = ibuf + 4;    // [256]
        int* nofs = ibuf + 260;  // [256]
        int* ws   = ibuf + 516;  // [4]
        int* wp   = ibuf + 520;  // [4]
        const int b = (int)blockIdx.x - g2Grid;

        int part = 0;
        for (int i = tid; i < b; i += 256) part += bcursor[i * BCS];
#pragma unroll
        for (int off = 32; off >= 1; off >>= 1) part += __shfl_xor(part, off);
        if ((tid & 63) == 0) red[tid >> 6] = part;
        __syncthreads();
        const int base = red[0] + red[1] + red[2] + red[3];

        const int cnt = min(bcursor[b * BCS], EBUF_CAP);
        const int* eb = ebuf + b * EBUF_CAP;

        ndeg[tid] = 0;
        __syncthreads();
        for (int j = tid; j < cnt; j += 256)
            atomicAdd(&ndeg[eb[j] & (NPB - 1)], 1);
        __syncthreads();

        const int lane = tid & 63, wid = tid >> 6;
        const int v = ndeg[tid];
        int x = v;
#pragma unroll
        for (int off = 1; off < 64; off <<= 1) {
            const int y = __shfl_up(x, off);
            if (lane >= off) x += y;
        }
        if (lane == 63) ws[wid] = x;
        __syncthreads();
        if (tid == 0) { int s = 0; for (int w = 0; w < 4; ++w) { wp[w] = s; s += ws[w]; } }
        __syncthreads();
        const int excl = x - v + wp[wid];
        nofs[tid] = excl;
        const int node = (b << NPB_SHIFT) + tid;
        if (node < N) offs[node] = base + excl;
        if (b == 0 && tid == 0) offs[N] = E;
        ndeg[tid] = 0;
        __syncthreads();

        for (int j = tid; j < cnt; j += 256) {
            const int e = eb[j];
            const int d = e & (NPB - 1);
            const int p = atomicAdd(&ndeg[d], 1);
            csr[base + nofs[d] + p] = e >> NPB_SHIFT;
        }
        return;
    }

    // ---- gemm2 ----
    u16 (*WtL)[136] = (u16(*)[136])smem;
    for (int i = tid; i < 2048; i += 256)
        *(uint4*)&WtL[i >> 4][(i & 15) * 8] = ((const uint4*)Wt_msg)[i];

    const int lane = tid & 63, wave = tid >> 6;
    const int lrow = lane & 15, lk = lane >> 4;
    const int r0 = (int)blockIdx.x * 64 + wave * 16;
    const int arow = r0 + lrow;
    const bool rowok = arow < rows;

    short8v a[4];
#pragma unroll
    for (int ks = 0; ks < 4; ++ks) {
        short8v av = {};
        if (rowok) av = *(const short8v*)(ns + (size_t)arow * 128 + ks * 32 + lk * 8);
        a[ks] = av;
    }
    __syncthreads();

    f32x4 acc[8];
#pragma unroll
    for (int n = 0; n < 8; ++n) acc[n] = (f32x4){0.f, 0.f, 0.f, 0.f};
#pragma unroll
    for (int ks = 0; ks < 4; ++ks) {
#pragma unroll
        for (int n = 0; n < 8; ++n) {
            const short8v b = *(const short8v*)&WtL[n * 16 + lrow][ks * 32 + lk * 8];
            acc[n] = __builtin_amdgcn_mfma_f32_16x16x32_bf16(a[ks], b, acc[n], 0, 0, 0);
        }
    }
#pragma unroll
    for (int reg = 0; reg < 4; ++reg) {
        const int row = r0 + lk * 4 + reg;
        if (row >= rows) continue;
#pragma unroll
        for (int n = 0; n < 8; ++n) {
            const float v = fmaxf(acc[n][reg] + b_msg[n * 16 + lrow], 0.f);
            msg8[(size_t)row * 128 + n * 16 + lrow] = f2fp8(v);
        }
    }
}

// ---------------- gather body (512 thr: 64 nodes/block, 8 lanes/node) ----------------
__device__ __forceinline__ void acc16(float* acc, const uint4 u) {
    fp8x4_acc(u.x, acc);
    fp8x4_acc(u.y, acc + 4);
    fp8x4_acc(u.z, acc + 8);
    fp8x4_acc(u.w, acc + 12);
}

__device__ __forceinline__ void gather_body(
    int tid, int widx, int rowBeg, int rowEnd,
    const int* __restrict__ offs, const int* __restrict__ csr,
    const u8* __restrict__ msg8, u16* __restrict__ agg)
{
    const int node = rowBeg + widx * 64 + (tid >> 3);
    if (node >= rowEnd) return;
    const int c16 = tid & 7;
    int j = offs[node];
    const int j1 = offs[node + 1];
    const uint4* mv = (const uint4*)msg8;
    float acc[16];
#pragma unroll
    for (int q = 0; q < 16; ++q) acc[q] = 0.f;
    for (; j + 3 < j1; j += 4) {
        const int s0 = csr[j], s1 = csr[j + 1], s2 = csr[j + 2], s3 = csr[j + 3];
        const uint4 u0 = mv[(size_t)s0 * 8 + c16];
        const uint4 u1 = mv[(size_t)s1 * 8 + c16];
        const uint4 u2 = mv[(size_t)s2 * 8 + c16];
        const uint4 u3 = mv[(size_t)s3 * 8 + c16];
        acc16(acc, u0); acc16(acc, u1); acc16(acc, u2); acc16(acc, u3);
    }
    for (; j < j1; ++j)
        acc16(acc, mv[(size_t)csr[j] * 8 + c16]);

    u16 r[16];
#pragma unroll
    for (int q = 0; q < 16; ++q) r[q] = f2bf(acc[q]);
    uint4* ap = (uint4*)(agg + (size_t)node * 128 + c16 * 16);
    ap[0] = *(uint4*)r;
    ap[1] = *(uint4*)(r + 8);
}

// ---------------- gemm3+heads body (512 thr, 128 rows/block-index) ----------------
__device__ __forceinline__ void gemm3_head_body(
    u16* smem_raw, int tid, int widx, int rowBeg, int rowEnd,
    const u16* __restrict__ agg, const u16* __restrict__ ns,
    const u16* __restrict__ Wt_upd, const float* __restrict__ b_upd,
    float* __restrict__ Cf, const u16* __restrict__ Wh,
    const float* __restrict__ ba1, const float* __restrict__ Wa2, const float* __restrict__ ba2,
    const float* __restrict__ bc1, const float* __restrict__ Wc2, const float* __restrict__ bc2,
    float* __restrict__ logits, float* __restrict__ crit)
{
    u16 (*WtL)[136] = (u16(*)[136])smem_raw;
    const uint4* W4 = (const uint4*)Wt_upd;

    for (int i = tid; i < 2048; i += 512)
        *(uint4*)&WtL[i >> 4][(i & 15) * 8] = W4[(i >> 4) * 32 + (i & 15)];

    const int lane = tid & 63, wave = tid >> 6;
    const int lrow = lane & 15, lk = lane >> 4;
    const int r0 = rowBeg + widx * 128 + wave * 16;
    const int arow = r0 + lrow;
    const bool rowok = arow < rowEnd;

    short8v a[4], a2[4];
#pragma unroll
    for (int ks = 0; ks < 4; ++ks) {
        short8v av = {}, av2 = {};
        if (rowok) {
            av  = *(const short8v*)(agg + (size_t)arow * 128 + ks * 32 + lk * 8);
            av2 = *(const short8v*)(ns  + (size_t)arow * 128 + ks * 32 + lk * 8);
        }
        a[ks] = av; a2[ks] = av2;
    }
    __syncthreads();

    f32x4 acc[8];
#pragma unroll
    for (int n = 0; n < 8; ++n) acc[n] = (f32x4){0.f, 0.f, 0.f, 0.f};
#pragma unroll
    for (int ks = 0; ks < 4; ++ks) {
#pragma unroll
        for (int n = 0; n < 8; ++n) {
            const short8v b = *(const short8v*)&WtL[n * 16 + lrow][ks * 32 + lk * 8];
            acc[n] = __builtin_amdgcn_mfma_f32_16x16x32_bf16(a[ks], b, acc[n], 0, 0, 0);
        }
    }

    __syncthreads();
    for (int i = tid; i < 2048; i += 512)
        *(uint4*)&WtL[i >> 4][(i & 15) * 8] = W4[(i >> 4) * 32 + 16 + (i & 15)];
    __syncthreads();

#pragma unroll
    for (int ks = 0; ks < 4; ++ks) {
#pragma unroll
        for (int n = 0; n < 8; ++n) {
            const short8v b = *(const short8v*)&WtL[n * 16 + lrow][ks * 32 + lk * 8];
            acc[n] = __builtin_amdgcn_mfma_f32_16x16x32_bf16(a2[ks], b, acc[n], 0, 0, 0);
        }
    }

    u16 uv[4][8];
#pragma unroll
    for (int reg = 0; reg < 4; ++reg) {
        const int row = r0 + lk * 4 + reg;
#pragma unroll
        for (int n = 0; n < 8; ++n) {
            const float v = fmaxf(acc[n][reg] + b_upd[n * 16 + lrow], 0.f);
            uv[reg][n] = f2bf(v);
            if (row < rowEnd) Cf[(size_t)row * 128 + n * 16 + lrow] = v;
        }
    }
    __syncthreads();

    u16 (*uT)[16][136] = (u16(*)[16][136])smem_raw;
#pragma unroll
    for (int reg = 0; reg < 4; ++reg) {
        const int lr = lk * 4 + reg;
#pragma unroll
        for (int n = 0; n < 8; ++n)
            uT[wave][lr][n * 16 + lrow] = uv[reg][n];
    }
    __syncthreads();

    short8v ah[4], b0[4], b1[4];
#pragma unroll
    for (int ks = 0; ks < 4; ++ks) {
        const int k = ks * 32 + lk * 8;
        ah[ks] = *(const short8v*)&uT[wave][lrow][k];
        b0[ks] = *(const short8v*)(Wh + (size_t)lrow * 128 + k);
        b1[ks] = *(const short8v*)(Wh + (size_t)(16 + lrow) * 128 + k);
    }
    f32x4 acc0 = (f32x4){0.f, 0.f, 0.f, 0.f};
    f32x4 acc1 = (f32x4){0.f, 0.f, 0.f, 0.f};
#pragma unroll
    for (int ks = 0; ks < 4; ++ks) {
        acc0 = __builtin_amdgcn_mfma_f32_16x16x32_bf16(ah[ks], b0[ks], acc0, 0, 0, 0);
        acc1 = __builtin_amdgcn_mfma_f32_16x16x32_bf16(ah[ks], b1[ks], acc1, 0, 0, 0);
    }
    const float wa = Wa2[lrow], wc = Wc2[lrow];
    const float ha = ba1[lrow], hc = bc1[lrow];
    const float b2a = ba2[0],   b2c = bc2[0];
#pragma unroll
    for (int reg = 0; reg < 4; ++reg) {
        float pa = fmaxf(acc0[reg] + ha, 0.f) * wa;
        float pc = fmaxf(acc1[reg] + hc, 0.f) * wc;
#pragma unroll
        for (int off = 8; off >= 1; off >>= 1) {
            pa += __shfl_xor(pa, off);
            pc += __shfl_xor(pc, off);
        }
        const int row = r0 + lk * 4 + reg;
        if (lrow == 0 && row < rowEnd) {
            logits[row] = pa + b2a;
            crit[row]   = pc + b2c;
        }
    }
}

// ---------------- D: gather rows [0, Nh) ----------------
__global__ __launch_bounds__(512) void gather_kernel(
    const int* __restrict__ offs, const int* __restrict__ csr,
    const u8* __restrict__ msg8, u16* __restrict__ agg, int rowBeg, int rowEnd)
{
    gather_body(threadIdx.x, blockIdx.x, rowBeg, rowEnd, offs, csr, msg8, agg);
}

// ---------------- M: gemm3(h0) || gather(h1), merged ----------------
__global__ __launch_bounds__(512) void gather_gemm3_kernel(
    const int* __restrict__ offs, const int* __restrict__ csr,
    const u8* __restrict__ msg8, u16* __restrict__ agg,
    int gRowBeg, int gRowEnd,
    const u16* __restrict__ ns,
    const u16* __restrict__ Wt_upd, const float* __restrict__ b_upd,
    float* __restrict__ Cf, const u16* __restrict__ Wh,
    const float* __restrict__ ba1, const float* __restrict__ Wa2, const float* __restrict__ ba2,
    const float* __restrict__ bc1, const float* __restrict__ Wc2, const float* __restrict__ bc2,
    float* __restrict__ logits, float* __restrict__ crit,
    int eRowBeg, int eRowEnd, int eBlocks)
{
    __shared__ u16 smem[128 * 136];
    const int tid = threadIdx.x;
    if ((int)blockIdx.x < eBlocks) {
        gemm3_head_body(smem, tid, blockIdx.x, eRowBeg, eRowEnd,
                        agg, ns, Wt_upd, b_upd, Cf, Wh,
                        ba1, Wa2, ba2, bc1, Wc2, bc2, logits, crit);
    } else {
        gather_body(tid, (int)blockIdx.x - eBlocks, gRowBeg, gRowEnd, offs, csr, msg8, agg);
    }
}

// ---------------- E: gemm3 rows [Nh, N) ----------------
__global__ __launch_bounds__(512) void gemm3_head_kernel(
    const u16* __restrict__ agg, const u16* __restrict__ ns,
    const u16* __restrict__ Wt_upd, const float* __restrict__ b_upd,
    float* __restrict__ Cf, const u16* __restrict__ Wh,
    const float* __restrict__ ba1, const float* __restrict__ Wa2, const float* __restrict__ ba2,
    const float* __restrict__ bc1, const float* __restrict__ Wc2, const float* __restrict__ bc2,
    float* __restrict__ logits, float* __restrict__ crit, int rowBeg, int rowEnd)
{
    __shared__ u16 smem[128 * 136];
    gemm3_head_body(smem, threadIdx.x, blockIdx.x, rowBeg, rowEnd,
                    agg, ns, Wt_upd, b_upd, Cf, Wh,
                    ba1, Wa2, ba2, bc1, Wc2, bc2, logits, crit);
}

// ---------------- F: per-graph finalize ----------------
__device__ __forceinline__ float blockRedMax(float v, float* red) {
#pragma unroll
    for (int o = 32; o >= 1; o >>= 1) v = fmaxf(v, __shfl_xor(v, o));
    const int w = threadIdx.x >> 6;
    __syncthreads();
    if ((threadIdx.x & 63) == 0) red[w] = v;
    __syncthreads();
    if (threadIdx.x < 16) {
        float x = red[threadIdx.x];
#pragma unroll
        for (int o = 8; o >= 1; o >>= 1) x = fmaxf(x, __shfl_xor(x, o));
        if (threadIdx.x == 0) red[0] = x;
    }
    __syncthreads();
    const float r = red[0];
    __syncthreads();
    return r;
}

__device__ __forceinline__ float blockRedSum(float v, float* red) {
#pragma unroll
    for (int o = 32; o >= 1; o >>= 1) v += __shfl_xor(v, o);
    const int w = threadIdx.x >> 6;
    __syncthreads();
    if ((threadIdx.x & 63) == 0) red[w] = v;
    __syncthreads();
    if (threadIdx.x < 16) {
        float x = red[threadIdx.x];
#pragma unroll
        for (int o = 8; o >= 1; o >>= 1) x += __shfl_xor(x, o);
        if (threadIdx.x == 0) red[0] = x;
    }
    __syncthreads();
    const float r = red[0];
    __syncthreads();
    return r;
}

__global__ __launch_bounds__(1024) void finalize_kernel(
    const float* __restrict__ logits, const float* __restrict__ crit,
    const int* __restrict__ actions, float* __restrict__ out, int NP, int G)
{
    __shared__ float slog[12512];
    __shared__ float red[16];
    const int g = blockIdx.x;
    const int tid = threadIdx.x;
    const float* lg = logits + (long long)g * NP;
    const float* cg = crit   + (long long)g * NP;

    float lmax = -3.402823466e38f, cmax = -3.402823466e38f, csum = 0.f;
    for (int i = tid; i < NP; i += 1024) {
        const float l = lg[i], c = cg[i];
        slog[i] = l;
        lmax = fmaxf(lmax, l);
        cmax = fmaxf(cmax, c);
        csum += c;
    }
    __syncthreads();
    lmax = blockRedMax(lmax, red);
    cmax = blockRedMax(cmax, red);
    csum = blockRedSum(csum, red);

    float zsum = 0.f, ssum = 0.f;
    for (int i = tid; i < NP; i += 1024) {
        const float s = slog[i];
        const float e = expf(s - lmax);
        zsum += e;
        ssum += s * e;
    }
    zsum = blockRedSum(zsum, red);
    ssum = blockRedSum(ssum, red);

    if (tid == 0) {
        const int a = actions[g];
        const float sa   = slog[a];
        const float logZ = logf(zsum) + lmax;
        const float lp   = sa - logZ;
        const float H    = logZ - ssum / zsum;
        const float v    = cmax * 0.5f + (csum / (float)NP) * 0.5f;
        out[g]         = (float)a;
        out[G + g]     = lp;
        out[2 * G + g] = H;
        out[3 * G + g] = v;
    }
}

extern "C" void kernel_launch(void* const* d_in, const int* in_sizes, int n_in,
                              void* d_out, int out_size, void* d_ws, size_t ws_size,
                              hipStream_t stream)
{
    const float* inputs = (const float*)d_in[0];
    const float* W_in   = (const float*)d_in[1];
    const float* b_in   = (const float*)d_in[2];
    const float* W_msg  = (const float*)d_in[3];
    const float* b_msg  = (const float*)d_in[4];
    const float* W_upd  = (const float*)d_in[5];
    const float* b_upd  = (const float*)d_in[6];
    const float* W_a1   = (const float*)d_in[7];
    const float* b_a1   = (const float*)d_in[8];
    const float* W_a2   = (const float*)d_in[9];
    const float* b_a2   = (const float*)d_in[10];
    const float* W_c1   = (const float*)d_in[11];
    const float* b_c1   = (const float*)d_in[12];
    const float* W_c2   = (const float*)d_in[13];
    const float* b_c2   = (const float*)d_in[14];
    const int* edge_src = (const int*)d_in[15];
    const int* edge_dst = (const int*)d_in[16];
    const int* actions  = (const int*)d_in[17];

    const int N  = in_sizes[0] / 128;
    const int E  = in_sizes[15];
    const int G  = in_sizes[17];
    const int NP = N / G;
    const int nbuk = (N + NPB - 1) >> NPB_SHIFT;

    float* out = (float*)d_out;                     // updates [N*128] f32 + 4G tail

    // workspace layout
    u16* ns_bf  = (u16*)d_ws;                       // [N*128] u16
    u16* agg_bf = ns_bf + (size_t)N * 128;          // [N*128] u16
    u8*  msg8   = (u8*)(agg_bf + (size_t)N * 128);  // [N*128] u8
    u16* Wt_in  = (u16*)(msg8 + (size_t)N * 128);   // [128*128]
    u16* Wt_msg = Wt_in  + 128 * 128;               // [128*128]
    u16* Wt_upd = Wt_msg + 128 * 128;               // [128*256]
    u16* Wh     = Wt_upd + 128 * 256;               // [32*128]
    float* logits = (float*)(Wh + 32 * 128);        // [N]
    float* crit   = logits + N;                     // [N]
    int*   offs    = (int*)(crit + N);              // [N+1]
    int*   csr     = offs + (N + 1);                // [E]
    int*   bcursor = csr + E;                       // [MAX_BUK * BCS]
    int*   ebuf    = bcursor + MAX_BUK * BCS;       // [nbuk * EBUF_CAP]

    const int binGrid = (E + BIN_CHUNK - 1) / BIN_CHUNK;          // 391
    const int convGrid = (69632 + MAX_BUK * BCS + 255) / 256;     // 304
    const int g1Grid  = (N + 255) / 256;                          // 391
    const int g2Grid  = (N + 63) / 64;                            // 1563

    const int Nh = ((N / 2) + 127) & ~127;          // half split, 128-aligned
    const int gGridH0 = (Nh + 63) / 64;             // gather blocks for [0, Nh)
    const int gGridH1 = (N - Nh + 63) / 64;         // gather blocks for [Nh, N)
    const int eGridH0 = Nh / 128;                   // gemm3 blocks for [0, Nh)
    const int eGridH1 = (N - Nh + 127) / 128;       // gemm3 blocks for [Nh, N)

    // A: weight conversions + bcursor zeroing
    conv_kernel<<<convGrid, 256, 0, stream>>>(
        W_in, W_msg, W_upd, W_a1, W_c1, Wt_in, Wt_msg, Wt_upd, Wh, bcursor);
    // B: gemm1 || edge binning (interleaved)
    bin_gemm1_kernel<<<binGrid + g1Grid, 1024, 0, stream>>>(
        edge_src, edge_dst, bcursor, ebuf, E, nbuk, binGrid, g1Grid,
        inputs, Wt_in, b_in, ns_bf, N);
    // C: gemm2 first, CSR finalize last
    csr_gemm2_kernel<<<g2Grid + nbuk, 256, 0, stream>>>(
        ebuf, bcursor, offs, csr, N, E, nbuk,
        ns_bf, Wt_msg, b_msg, msg8, N, g2Grid);
    // D: gather first half
    gather_kernel<<<gGridH0, 512, 0, stream>>>(offs, csr, msg8, agg_bf, 0, Nh);
    // M: gemm3(h0) || gather(h1)
    gather_gemm3_kernel<<<eGridH0 + gGridH1, 512, 0, stream>>>(
        offs, csr, msg8, agg_bf, Nh, N,
        ns_bf, Wt_upd, b_upd, out, Wh,
        b_a1, W_a2, b_a2, b_c1, W_c2, b_c2, logits, crit,
        0, Nh, eGridH0);
    // E: gemm3 second half
    gemm3_head_kernel<<<eGridH1, 512, 0, stream>>>(
        agg_bf, ns_bf, Wt_upd, b_upd, out, Wh,
        b_a1, W_a2, b_a2, b_c1, W_c2, b_c2, logits, crit, Nh, N);
    // F: per-graph outputs
    finalize_kernel<<<G, 1024, 0, stream>>>(logits, crit, actions, out + (size_t)N * 128, NP, G);
}

// Round 21
// 145.530 us; speedup vs baseline: 1.1705x; 1.1705x over previous
//
#include <hip/hip_runtime.h>
#include <math.h>

typedef unsigned short u16;
typedef unsigned int   u32;
typedef unsigned char  u8;
typedef __attribute__((ext_vector_type(8))) short short8v;
typedef __attribute__((ext_vector_type(4))) float f32x4;
typedef __attribute__((ext_vector_type(2))) float f32x2;

__device__ __forceinline__ u16 f2bf(float x) {
    u32 u = __float_as_uint(x);
    u += 0x7FFFu + ((u >> 16) & 1u);   // RNE
    return (u16)(u >> 16);
}

#if __has_builtin(__builtin_amdgcn_cvt_pk_fp8_f32) && __has_builtin(__builtin_amdgcn_cvt_pk_f32_fp8)
#define HW_FP8 1
#endif

// encode one fp8 e4m3fn from v >= 0 (relu output)
__device__ __forceinline__ u8 f2fp8(float v) {
#ifdef HW_FP8
    return (u8)(__builtin_amdgcn_cvt_pk_fp8_f32(v, v, 0, false) & 0xFF);
#else
    if (v < 0.015625f) return (u8)__float2int_rn(v * 512.0f);   // subnormal
    u32 b = __float_as_uint(fminf(v, 448.0f));
    b += 0x7FFFF + ((b >> 20) & 1);                              // RNE to 3 mant bits
    return (u8)((((b >> 23) - 120) << 3) | ((b >> 20) & 7));
#endif
}

__device__ __forceinline__ void fp8x4_acc(u32 w, float* acc) {
#ifdef HW_FP8
    const f32x2 lo = __builtin_amdgcn_cvt_pk_f32_fp8(w, false);
    const f32x2 hi = __builtin_amdgcn_cvt_pk_f32_fp8(w, true);
    acc[0] += lo[0]; acc[1] += lo[1]; acc[2] += hi[0]; acc[3] += hi[1];
#else
#pragma unroll
    for (int i = 0; i < 4; ++i) {
        const u32 b = (w >> (8 * i)) & 0xFF;
        const u32 e = (b >> 3) & 15, m = b & 7;
        acc[i] += e ? __uint_as_float(((e + 120) << 23) | (m << 20))
                    : (float)m * 0x1p-9f;
    }
#endif
}

#define NPB        256
#define NPB_SHIFT  8
#define EBUF_CAP   4608
#define MAX_BUK    512
#define BCS        16      // bcursor stride in ints (64 B -> one cacheline per bucket)
#define BIN_CHUNK  4096    // edges per bin block (4 per thread at 1024 threads)

// ---------------- A: convert weights + zero bcursor ----------------
__global__ __launch_bounds__(256) void conv_kernel(
    const float* __restrict__ W_in, const float* __restrict__ W_msg,
    const float* __restrict__ W_upd,
    const float* __restrict__ Wa1, const float* __restrict__ Wc1,
    u16* __restrict__ Wt_in, u16* __restrict__ Wt_msg,
    u16* __restrict__ Wt_upd, u16* __restrict__ Wh,
    int* __restrict__ bcursor)
{
    const int idx = blockIdx.x * 256 + threadIdx.x;
    if (idx < 16384) {                       // Wt_in [128 cols][128 k]
        const int c = idx >> 7, k = idx & 127;
        Wt_in[c * 128 + k] = f2bf(W_in[k * 128 + c]);
    } else if (idx < 32768) {                // Wt_msg
        const int i = idx - 16384;
        const int c = i >> 7, k = i & 127;
        Wt_msg[c * 128 + k] = f2bf(W_msg[k * 128 + c]);
    } else if (idx < 65536) {                // Wt_upd [128 cols][256 k]
        const int i = idx - 32768;
        const int c = i >> 8, k = i & 255;
        Wt_upd[c * 256 + k] = f2bf(W_upd[k * 128 + c]);
    } else if (idx < 69632) {                // Wh [32 cols][128 k]
        const int i = idx - 65536;
        const int col = i >> 7, k = i & 127;
        const float v = (col < 16) ? Wa1[k * 16 + col] : Wc1[k * 16 + (col - 16)];
        Wh[col * 128 + k] = f2bf(v);
    } else if (idx < 69632 + MAX_BUK * BCS) { // zero bucket cursors
        bcursor[idx - 69632] = 0;
    }
}

// ---------------- B: gemm1 || bin edges, INTERLEAVED (1024 thr) ----------------
__global__ __launch_bounds__(1024) void bin_gemm1_kernel(
    const int* __restrict__ src, const int* __restrict__ dst,
    int* __restrict__ bcursor, int* __restrict__ ebuf,
    int E, int nbuk, int binGrid, int g1Grid,
    const float* __restrict__ X, const u16* __restrict__ Wt_in,
    const float* __restrict__ b_in, u16* __restrict__ ns, int rows)
{
    __shared__ u16 smem[128 * 136];   // 34816 B
    const int tid = threadIdx.x;

    const int mn   = min(binGrid, g1Grid);
    const int half = 2 * mn;
    int role, widx;   // role 0 = gemm1, 1 = bin
    if ((int)blockIdx.x < half) {
        role = (int)blockIdx.x & 1;
        widx = (int)blockIdx.x >> 1;
    } else {
        const int r = (int)blockIdx.x - half;
        role = (binGrid > g1Grid) ? 1 : 0;
        widx = mn + r;
    }

    if (role == 1) {
        int* lcount = (int*)smem;            // [MAX_BUK]
        int* lbase  = lcount + MAX_BUK;      // [MAX_BUK]
        const int e0 = widx * BIN_CHUNK;
        const int e1 = min(e0 + BIN_CHUNK, E);
        for (int b = tid; b < nbuk; b += 1024) lcount[b] = 0;
        __syncthreads();

        int pay[4];
        u32 brk[4];
#pragma unroll
        for (int k = 0; k < 4; ++k) {
            const int i = e0 + tid + k * 1024;
            int payv = 0; u32 brkv = 0xFFFFFFFFu;
            if (i < e1) {
                const int d = dst[i];
                const int b = d >> NPB_SHIFT;
                const int r = atomicAdd(&lcount[b], 1);
                payv = (src[i] << NPB_SHIFT) | (d & (NPB - 1));
                brkv = ((u32)b << 16) | (u32)r;
            }
            pay[k] = payv; brk[k] = brkv;
        }
        __syncthreads();

        for (int b = tid; b < nbuk; b += 1024) {
            const int c = lcount[b];
            lbase[b] = c ? atomicAdd(&bcursor[b * BCS], c) : 0;
        }
        __syncthreads();

#pragma unroll
        for (int k = 0; k < 4; ++k) {
            if (brk[k] != 0xFFFFFFFFu) {
                const int b = (int)(brk[k] >> 16);
                const int p = lbase[b] + (int)(brk[k] & 0xFFFFu);
                ebuf[b * EBUF_CAP + min(p, EBUF_CAP - 1)] = pay[k];
            }
        }
        return;
    }

    // ---- gemm1: 16 waves x 16 rows = 256 rows/block ----
    u16 (*WtL)[136] = (u16(*)[136])smem;
    for (int i = tid; i < 2048; i += 1024)
        *(uint4*)&WtL[i >> 4][(i & 15) * 8] = ((const uint4*)Wt_in)[i];

    const int lane = tid & 63, wave = tid >> 6;
    const int lrow = lane & 15, lk = lane >> 4;
    const int r0 = widx * 256 + wave * 16;
    const int arow = r0 + lrow;
    const bool rowok = arow < rows;

    short8v a[4];
#pragma unroll
    for (int ks = 0; ks < 4; ++ks) {
        const int k = ks * 32 + lk * 8;
        short8v av = {};
        if (rowok) {
            const float* pf = X + (size_t)arow * 128 + k;
            const float4 x0 = *(const float4*)pf;
            const float4 x1 = *(const float4*)(pf + 4);
            u16 t[8] = {f2bf(x0.x), f2bf(x0.y), f2bf(x0.z), f2bf(x0.w),
                        f2bf(x1.x), f2bf(x1.y), f2bf(x1.z), f2bf(x1.w)};
            av = *(short8v*)t;
        }
        a[ks] = av;
    }
    __syncthreads();

    f32x4 acc[8];
#pragma unroll
    for (int n = 0; n < 8; ++n) acc[n] = (f32x4){0.f, 0.f, 0.f, 0.f};
#pragma unroll
    for (int ks = 0; ks < 4; ++ks) {
#pragma unroll
        for (int n = 0; n < 8; ++n) {
            const short8v b = *(const short8v*)&WtL[n * 16 + lrow][ks * 32 + lk * 8];
            acc[n] = __builtin_amdgcn_mfma_f32_16x16x32_bf16(a[ks], b, acc[n], 0, 0, 0);
        }
    }
#pragma unroll
    for (int reg = 0; reg < 4; ++reg) {
        const int row = r0 + lk * 4 + reg;
        if (row >= rows) continue;
#pragma unroll
        for (int n = 0; n < 8; ++n) {
            const float v = fmaxf(acc[n][reg] + b_in[n * 16 + lrow], 0.f);
            ns[(size_t)row * 128 + n * 16 + lrow] = f2bf(v);
        }
    }
}

// ---------------- C: gemm2 first, build_csr last (256 thr) ----------------
__global__ __launch_bounds__(256) void csr_gemm2_kernel(
    const int* __restrict__ ebuf, const int* __restrict__ bcursor,
    int* __restrict__ offs, int* __restrict__ csr, int N, int E, int nbuk,
    const u16* __restrict__ ns, const u16* __restrict__ Wt_msg,
    const float* __restrict__ b_msg, u8* __restrict__ msg8, int rows, int g2Grid)
{
    __shared__ u16 smem[128 * 136];   // 34816 B
    const int tid = threadIdx.x;

    if ((int)blockIdx.x >= g2Grid) {
        int* ibuf = (int*)smem;
        int* red  = ibuf;        // [4]
        int* ndeg = ibuf + 4;    // [256]
        int* nofs = ibuf + 260;  // [256]
        int* ws   = ibuf + 516;  // [4]
        int* wp   = ibuf + 520;  // [4]
        const int b = (int)blockIdx.x - g2Grid;

        int part = 0;
        for (int i = tid; i < b; i += 256) part += bcursor[i * BCS];
#pragma unroll
        for (int off = 32; off >= 1; off >>= 1) part += __shfl_xor(part, off);
        if ((tid & 63) == 0) red[tid >> 6] = part;
        __syncthreads();
        const int base = red[0] + red[1] + red[2] + red[3];

        const int cnt = min(bcursor[b * BCS], EBUF_CAP);
        const int* eb = ebuf + b * EBUF_CAP;

        ndeg[tid] = 0;
        __syncthreads();
        for (int j = tid; j < cnt; j += 256)
            atomicAdd(&ndeg[eb[j] & (NPB - 1)], 1);
        __syncthreads();

        const int lane = tid & 63, wid = tid >> 6;
        const int v = ndeg[tid];
        int x = v;
#pragma unroll
        for (int off = 1; off < 64; off <<= 1) {
            const int y = __shfl_up(x, off);
            if (lane >= off) x += y;
        }
        if (lane == 63) ws[wid] = x;
        __syncthreads();
        if (tid == 0) { int s = 0; for (int w = 0; w < 4; ++w) { wp[w] = s; s += ws[w]; } }
        __syncthreads();
        const int excl = x - v + wp[wid];
        nofs[tid] = excl;
        const int node = (b << NPB_SHIFT) + tid;
        if (node < N) offs[node] = base + excl;
        if (b == 0 && tid == 0) offs[N] = E;
        ndeg[tid] = 0;
        __syncthreads();

        for (int j = tid; j < cnt; j += 256) {
            const int e = eb[j];
            const int d = e & (NPB - 1);
            const int p = atomicAdd(&ndeg[d], 1);
            csr[base + nofs[d] + p] = e >> NPB_SHIFT;
        }
        return;
    }

    // ---- gemm2 ----
    u16 (*WtL)[136] = (u16(*)[136])smem;
    for (int i = tid; i < 2048; i += 256)
        *(uint4*)&WtL[i >> 4][(i & 15) * 8] = ((const uint4*)Wt_msg)[i];

    const int lane = tid & 63, wave = tid >> 6;
    const int lrow = lane & 15, lk = lane >> 4;
    const int r0 = (int)blockIdx.x * 64 + wave * 16;
    const int arow = r0 + lrow;
    const bool rowok = arow < rows;

    short8v a[4];
#pragma unroll
    for (int ks = 0; ks < 4; ++ks) {
        short8v av = {};
        if (rowok) av = *(const short8v*)(ns + (size_t)arow * 128 + ks * 32 + lk * 8);
        a[ks] = av;
    }
    __syncthreads();

    f32x4 acc[8];
#pragma unroll
    for (int n = 0; n < 8; ++n) acc[n] = (f32x4){0.f, 0.f, 0.f, 0.f};
#pragma unroll
    for (int ks = 0; ks < 4; ++ks) {
#pragma unroll
        for (int n = 0; n < 8; ++n) {
            const short8v b = *(const short8v*)&WtL[n * 16 + lrow][ks * 32 + lk * 8];
            acc[n] = __builtin_amdgcn_mfma_f32_16x16x32_bf16(a[ks], b, acc[n], 0, 0, 0);
        }
    }
#pragma unroll
    for (int reg = 0; reg < 4; ++reg) {
        const int row = r0 + lk * 4 + reg;
        if (row >= rows) continue;
#pragma unroll
        for (int n = 0; n < 8; ++n) {
            const float v = fmaxf(acc[n][reg] + b_msg[n * 16 + lrow], 0.f);
            msg8[(size_t)row * 128 + n * 16 + lrow] = f2fp8(v);
        }
    }
}

// ---------------- D: gather (fp8 in, bf16 out): agg[n] = sum msg8[src] ----------------
__device__ __forceinline__ void acc16(float* acc, const uint4 u) {
    fp8x4_acc(u.x, acc);
    fp8x4_acc(u.y, acc + 4);
    fp8x4_acc(u.z, acc + 8);
    fp8x4_acc(u.w, acc + 12);
}

__global__ __launch_bounds__(256) void gather_fp8_kernel(
    const int* __restrict__ offs, const int* __restrict__ csr,
    const u8* __restrict__ msg8, u16* __restrict__ agg, int N)
{
    const int node = blockIdx.x * 32 + (threadIdx.x >> 3);
    if (node >= N) return;
    const int c16 = threadIdx.x & 7;      // 16-fp8 chunk of the 128-col row
    int j = offs[node];
    const int j1 = offs[node + 1];
    const uint4* mv = (const uint4*)msg8; // 8 uint4 per row
    float acc[16];
#pragma unroll
    for (int q = 0; q < 16; ++q) acc[q] = 0.f;
    for (; j + 3 < j1; j += 4) {
        const int s0 = csr[j], s1 = csr[j + 1], s2 = csr[j + 2], s3 = csr[j + 3];
        const uint4 u0 = mv[(size_t)s0 * 8 + c16];
        const uint4 u1 = mv[(size_t)s1 * 8 + c16];
        const uint4 u2 = mv[(size_t)s2 * 8 + c16];
        const uint4 u3 = mv[(size_t)s3 * 8 + c16];
        acc16(acc, u0); acc16(acc, u1); acc16(acc, u2); acc16(acc, u3);
    }
    for (; j < j1; ++j)
        acc16(acc, mv[(size_t)csr[j] * 8 + c16]);

    u16 r[16];
#pragma unroll
    for (int q = 0; q < 16; ++q) r[q] = f2bf(acc[q]);
    uint4* ap = (uint4*)(agg + (size_t)node * 128 + c16 * 16);
    ap[0] = *(uint4*)r;
    ap[1] = *(uint4*)(r + 8);
}

// ---------------- E: fused GEMM3 + heads (512 thr, 128 rows/block, two-half Wt staging) ----------------
__global__ __launch_bounds__(512) void gemm3_head_kernel(
    const u16* __restrict__ agg, const u16* __restrict__ ns,
    const u16* __restrict__ Wt_upd, const float* __restrict__ b_upd,
    float* __restrict__ Cf,
    const u16* __restrict__ Wh,
    const float* __restrict__ ba1, const float* __restrict__ Wa2, const float* __restrict__ ba2,
    const float* __restrict__ bc1, const float* __restrict__ Wc2, const float* __restrict__ bc2,
    float* __restrict__ logits, float* __restrict__ crit, int rows)
{
    __shared__ u16 smem[128 * 136];       // 34816 B
    u16 (*WtL)[136] = (u16(*)[136])smem;

    const int tid = threadIdx.x;
    const uint4* W4 = (const uint4*)Wt_upd;   // 32 uint4 per col (K=256)

    // stage K-half-0 (k = 0..127, the agg half)
    for (int i = tid; i < 2048; i += 512)
        *(uint4*)&WtL[i >> 4][(i & 15) * 8] = W4[(i >> 4) * 32 + (i & 15)];

    const int lane = tid & 63, wave = tid >> 6;      // wave 0..7
    const int lrow = lane & 15, lk = lane >> 4;
    const int r0 = blockIdx.x * 128 + wave * 16;
    const int arow = r0 + lrow;
    const bool rowok = arow < rows;

    // both A-operand halves loaded up front (overlap with staging)
    short8v a[4], a2[4];
#pragma unroll
    for (int ks = 0; ks < 4; ++ks) {
        short8v av = {}, av2 = {};
        if (rowok) {
            av  = *(const short8v*)(agg + (size_t)arow * 128 + ks * 32 + lk * 8);
            av2 = *(const short8v*)(ns  + (size_t)arow * 128 + ks * 32 + lk * 8);
        }
        a[ks] = av; a2[ks] = av2;
    }
    __syncthreads();   // half-0 staged

    f32x4 acc[8];
#pragma unroll
    for (int n = 0; n < 8; ++n) acc[n] = (f32x4){0.f, 0.f, 0.f, 0.f};
#pragma unroll
    for (int ks = 0; ks < 4; ++ks) {
#pragma unroll
        for (int n = 0; n < 8; ++n) {
            const short8v b = *(const short8v*)&WtL[n * 16 + lrow][ks * 32 + lk * 8];
            acc[n] = __builtin_amdgcn_mfma_f32_16x16x32_bf16(a[ks], b, acc[n], 0, 0, 0);
        }
    }

    __syncthreads();   // half-0 reads done; restage half-1 (k = 128..255, ns half)
    for (int i = tid; i < 2048; i += 512)
        *(uint4*)&WtL[i >> 4][(i & 15) * 8] = W4[(i >> 4) * 32 + 16 + (i & 15)];
    __syncthreads();

#pragma unroll
    for (int ks = 0; ks < 4; ++ks) {
#pragma unroll
        for (int n = 0; n < 8; ++n) {
            const short8v b = *(const short8v*)&WtL[n * 16 + lrow][ks * 32 + lk * 8];
            acc[n] = __builtin_amdgcn_mfma_f32_16x16x32_bf16(a2[ks], b, acc[n], 0, 0, 0);
        }
    }

    // epilogue: f32 updates -> d_out; bf16 in regs
    u16 uv[4][8];
#pragma unroll
    for (int reg = 0; reg < 4; ++reg) {
        const int row = r0 + lk * 4 + reg;
#pragma unroll
        for (int n = 0; n < 8; ++n) {
            const float v = fmaxf(acc[n][reg] + b_upd[n * 16 + lrow], 0.f);
            uv[reg][n] = f2bf(v);
            if (row < rows) Cf[(size_t)row * 128 + n * 16 + lrow] = v;
        }
    }
    __syncthreads();   // WtL reads complete

    // retile into reused LDS: uT[8][16][136] = 34816 B exactly; head B from global Wh
    u16 (*uT)[16][136] = (u16(*)[16][136])smem;
#pragma unroll
    for (int reg = 0; reg < 4; ++reg) {
        const int lr = lk * 4 + reg;
#pragma unroll
        for (int n = 0; n < 8; ++n)
            uT[wave][lr][n * 16 + lrow] = uv[reg][n];
    }
    __syncthreads();

    short8v ah[4], b0[4], b1[4];
#pragma unroll
    for (int ks = 0; ks < 4; ++ks) {
        const int k = ks * 32 + lk * 8;
        ah[ks] = *(const short8v*)&uT[wave][lrow][k];
        b0[ks] = *(const short8v*)(Wh + (size_t)lrow * 128 + k);
        b1[ks] = *(const short8v*)(Wh + (size_t)(16 + lrow) * 128 + k);
    }
    f32x4 acc0 = (f32x4){0.f, 0.f, 0.f, 0.f};
    f32x4 acc1 = (f32x4){0.f, 0.f, 0.f, 0.f};
#pragma unroll
    for (int ks = 0; ks < 4; ++ks) {
        acc0 = __builtin_amdgcn_mfma_f32_16x16x32_bf16(ah[ks], b0[ks], acc0, 0, 0, 0);
        acc1 = __builtin_amdgcn_mfma_f32_16x16x32_bf16(ah[ks], b1[ks], acc1, 0, 0, 0);
    }
    const float wa = Wa2[lrow], wc = Wc2[lrow];
    const float ha = ba1[lrow], hc = bc1[lrow];
    const float b2a = ba2[0],   b2c = bc2[0];
#pragma unroll
    for (int reg = 0; reg < 4; ++reg) {
        float pa = fmaxf(acc0[reg] + ha, 0.f) * wa;
        float pc = fmaxf(acc1[reg] + hc, 0.f) * wc;
#pragma unroll
        for (int off = 8; off >= 1; off >>= 1) {
            pa += __shfl_xor(pa, off);
            pc += __shfl_xor(pc, off);
        }
        const int row = r0 + lk * 4 + reg;
        if (lrow == 0 && row < rows) {
            logits[row] = pa + b2a;
            crit[row]   = pc + b2c;
        }
    }
}

// ---------------- F: per-graph finalize ----------------
__device__ __forceinline__ float blockRedMax(float v, float* red) {
#pragma unroll
    for (int o = 32; o >= 1; o >>= 1) v = fmaxf(v, __shfl_xor(v, o));
    const int w = threadIdx.x >> 6;
    __syncthreads();
    if ((threadIdx.x & 63) == 0) red[w] = v;
    __syncthreads();
    if (threadIdx.x < 16) {
        float x = red[threadIdx.x];
#pragma unroll
        for (int o = 8; o >= 1; o >>= 1) x = fmaxf(x, __shfl_xor(x, o));
        if (threadIdx.x == 0) red[0] = x;
    }
    __syncthreads();
    const float r = red[0];
    __syncthreads();
    return r;
}

__device__ __forceinline__ float blockRedSum(float v, float* red) {
#pragma unroll
    for (int o = 32; o >= 1; o >>= 1) v += __shfl_xor(v, o);
    const int w = threadIdx.x >> 6;
    __syncthreads();
    if ((threadIdx.x & 63) == 0) red[w] = v;
    __syncthreads();
    if (threadIdx.x < 16) {
        float x = red[threadIdx.x];
#pragma unroll
        for (int o = 8; o >= 1; o >>= 1) x += __shfl_xor(x, o);
        if (threadIdx.x == 0) red[0] = x;
    }
    __syncthreads();
    const float r = red[0];
    __syncthreads();
    return r;
}

__global__ __launch_bounds__(1024) void finalize_kernel(
    const float* __restrict__ logits, const float* __restrict__ crit,
    const int* __restrict__ actions, float* __restrict__ out, int NP, int G)
{
    __shared__ float slog[12512];
    __shared__ float red[16];
    const int g = blockIdx.x;
    const int tid = threadIdx.x;
    const float* lg = logits + (long long)g * NP;
    const float* cg = crit   + (long long)g * NP;

    float lmax = -3.402823466e38f, cmax = -3.402823466e38f, csum = 0.f;
    for (int i = tid; i < NP; i += 1024) {
        const float l = lg[i], c = cg[i];
        slog[i] = l;
        lmax = fmaxf(lmax, l);
        cmax = fmaxf(cmax, c);
        csum += c;
    }
    __syncthreads();
    lmax = blockRedMax(lmax, red);
    cmax = blockRedMax(cmax, red);
    csum = blockRedSum(csum, red);

    float zsum = 0.f, ssum = 0.f;
    for (int i = tid; i < NP; i += 1024) {
        const float s = slog[i];
        const float e = expf(s - lmax);
        zsum += e;
        ssum += s * e;
    }
    zsum = blockRedSum(zsum, red);
    ssum = blockRedSum(ssum, red);

    if (tid == 0) {
        const int a = actions[g];
        const float sa   = slog[a];
        const float logZ = logf(zsum) + lmax;
        const float lp   = sa - logZ;
        const float H    = logZ - ssum / zsum;
        const float v    = cmax * 0.5f + (csum / (float)NP) * 0.5f;
        out[g]         = (float)a;
        out[G + g]     = lp;
        out[2 * G + g] = H;
        out[3 * G + g] = v;
    }
}

extern "C" void kernel_launch(void* const* d_in, const int* in_sizes, int n_in,
                              void* d_out, int out_size, void* d_ws, size_t ws_size,
                              hipStream_t stream)
{
    const float* inputs = (const float*)d_in[0];
    const float* W_in   = (const float*)d_in[1];
    const float* b_in   = (const float*)d_in[2];
    const float* W_msg  = (const float*)d_in[3];
    const float* b_msg  = (const float*)d_in[4];
    const float* W_upd  = (const float*)d_in[5];
    const float* b_upd  = (const float*)d_in[6];
    const float* W_a1   = (const float*)d_in[7];
    const float* b_a1   = (const float*)d_in[8];
    const float* W_a2   = (const float*)d_in[9];
    const float* b_a2   = (const float*)d_in[10];
    const float* W_c1   = (const float*)d_in[11];
    const float* b_c1   = (const float*)d_in[12];
    const float* W_c2   = (const float*)d_in[13];
    const float* b_c2   = (const float*)d_in[14];
    const int* edge_src = (const int*)d_in[15];
    const int* edge_dst = (const int*)d_in[16];
    const int* actions  = (const int*)d_in[17];

    const int N  = in_sizes[0] / 128;
    const int E  = in_sizes[15];
    const int G  = in_sizes[17];
    const int NP = N / G;
    const int nbuk = (N + NPB - 1) >> NPB_SHIFT;

    float* out = (float*)d_out;                     // updates [N*128] f32 + 4G tail

    // workspace layout
    u16* ns_bf  = (u16*)d_ws;                       // [N*128] u16
    u16* agg_bf = ns_bf + (size_t)N * 128;          // [N*128] u16
    u8*  msg8   = (u8*)(agg_bf + (size_t)N * 128);  // [N*128] u8
    u16* Wt_in  = (u16*)(msg8 + (size_t)N * 128);   // [128*128]
    u16* Wt_msg = Wt_in  + 128 * 128;               // [128*128]
    u16* Wt_upd = Wt_msg + 128 * 128;               // [128*256]
    u16* Wh     = Wt_upd + 128 * 256;               // [32*128]
    float* logits = (float*)(Wh + 32 * 128);        // [N]
    float* crit   = logits + N;                     // [N]
    int*   offs    = (int*)(crit + N);              // [N+1]
    int*   csr     = offs + (N + 1);                // [E]
    int*   bcursor = csr + E;                       // [MAX_BUK * BCS]
    int*   ebuf    = bcursor + MAX_BUK * BCS;       // [nbuk * EBUF_CAP]

    const int binGrid = (E + BIN_CHUNK - 1) / BIN_CHUNK;          // 391
    const int convGrid = (69632 + MAX_BUK * BCS + 255) / 256;     // 304
    const int g1Grid  = (N + 255) / 256;                          // 391
    const int g2Grid  = (N + 63) / 64;                            // 1563
    const int g3Grid  = (N + 127) / 128;                          // 782

    // A: weight conversions + bcursor zeroing
    conv_kernel<<<convGrid, 256, 0, stream>>>(
        W_in, W_msg, W_upd, W_a1, W_c1, Wt_in, Wt_msg, Wt_upd, Wh, bcursor);
    // B: gemm1 || edge binning, interleaved block roles
    bin_gemm1_kernel<<<binGrid + g1Grid, 1024, 0, stream>>>(
        edge_src, edge_dst, bcursor, ebuf, E, nbuk, binGrid, g1Grid,
        inputs, Wt_in, b_in, ns_bf, N);
    // C: gemm2 first, CSR finalize last
    csr_gemm2_kernel<<<g2Grid + nbuk, 256, 0, stream>>>(
        ebuf, bcursor, offs, csr, N, E, nbuk,
        ns_bf, Wt_msg, b_msg, msg8, N, g2Grid);
    // D: agg (bf16) = segment_sum(msg8)
    gather_fp8_kernel<<<(N + 31) / 32, 256, 0, stream>>>(offs, csr, msg8, agg_bf, N);
    // E: updates + heads (fused, two-half weight staging, 8 waves/block)
    gemm3_head_kernel<<<g3Grid, 512, 0, stream>>>(
        agg_bf, ns_bf, Wt_upd, b_upd, out, Wh,
        b_a1, W_a2, b_a2, b_c1, W_c2, b_c2, logits, crit, N);
    // F: per-graph outputs
    finalize_kernel<<<G, 1024, 0, stream>>>(logits, crit, actions, out + (size_t)N * 128, NP, G);
}